// Round 18
// baseline (136.360 us; speedup 1.0000x reference)
//
#include <hip/hip_runtime.h>
#include <hip/hip_bf16.h>

#define NE 100
#define NB 4096
#define ND 256
#define NF 32
#define NH 16
#define NL 8
#define BT 256
#define S_REP 264     // repack row stride in floats

typedef float    floatx4 __attribute__((ext_vector_type(4)));
typedef _Float16 half8   __attribute__((ext_vector_type(8)));

#define NLOG2E -1.44269504088896f

__device__ __forceinline__ float sig2(float a) {   // a = -log2e*x ; sigmoid(x)
    return __builtin_amdgcn_rcpf(1.0f + __builtin_amdgcn_exp2f(a));
}

// R15 burst structure with the STORE SHAPE changed to mimic the harness
// fill kernel exactly: plain global_store_dword, 4B/lane, each wave
// instruction a 256B-contiguous aligned segment. Hypothesis: this pattern
// qualifies for the L2 fill-less-allocate fast path the fill uses to hit
// 6.9 TB/s, which our 1KB dwordx4 (NT ~4.4, plain-RFO ~3.5) never did.
// Repack reads become 64 x ds_read_b32 (2-way bank alias only - free).
__global__ __launch_bounds__(256, 2)
void bagae_mfma(const float* __restrict__ x,
                const int* __restrict__ idx,
                const float* __restrict__ We0, const float* __restrict__ be0,
                const float* __restrict__ We1, const float* __restrict__ be1,
                const float* __restrict__ Wl,  const float* __restrict__ bl,
                const float* __restrict__ Wd0, const float* __restrict__ bd0,
                const float* __restrict__ Wd1, const float* __restrict__ bd1,
                const float* __restrict__ Wo,  const float* __restrict__ bo,
                float* __restrict__ out)
{
    __shared__ float sPool[4 * 16 * S_REP];
    __shared__ float sBias[ND];          // -log2e * bo_e
    __shared__ float s_We0[NF * NH];
    __shared__ float s_We1[NH * NL];
    __shared__ float s_Wl [NL * NL];
    __shared__ float s_Wd0[NL * NH];
    __shared__ float s_Wd1[NH * NF];
    __shared__ float s_be0[NH], s_be1[NL], s_bl[NL], s_bd0[NH], s_bd1[NF];
    __shared__ int   s_idx[NF];

    _Float16* sA = reinterpret_cast<_Float16*>(sPool);           // 256x32 fp16 = 16KB
    _Float16* sB = reinterpret_cast<_Float16*>(sPool) + BT * NF; // 256x32 fp16 = 16KB

    const int tid = threadIdx.x;
    const int e   = blockIdx.y;
    const int b0  = blockIdx.x * BT;

    // ---- stage small per-estimator weights + scaled output bias ----
    {
        const float* We0e = We0 + e * (NF * NH);
        const float* Wd1e = Wd1 + e * (NH * NF);
        for (int i = tid; i < NF * NH; i += 256) { s_We0[i] = We0e[i]; s_Wd1[i] = Wd1e[i]; }
        sBias[tid] = bo[e * ND + tid] * NLOG2E;
        if (tid < NH * NL) { s_We1[tid] = We1[e * NH * NL + tid];
                             s_Wd0[tid] = Wd0[e * NL * NH + tid]; }
        if (tid < NL * NL) { s_Wl[tid]  = Wl [e * NL * NL + tid]; }
        if (tid < NF)      { s_idx[tid] = idx[e * NF + tid];
                             s_bd1[tid] = bd1[e * NF + tid]; }
        if (tid < NH)      { s_be0[tid] = be0[e * NH + tid];
                             s_bd0[tid] = bd0[e * NH + tid]; }
        if (tid < NL)      { s_be1[tid] = be1[e * NL + tid];
                             s_bl [tid] = bl [e * NL + tid]; }
    }

    // ---- stage B = (-log2e * Wo_e) column tid as fp16 fragments ----
    {
        const float* Woe = Wo + (long)e * NF * ND;
        float wcol[NF];
        #pragma unroll
        for (int k = 0; k < NF; ++k) wcol[k] = Woe[k * ND + tid];   // coalesced
        const int ct = tid >> 4, c16 = tid & 15;
        #pragma unroll
        for (int kc = 0; kc < 4; ++kc) {
            half8 v;
            #pragma unroll
            for (int j = 0; j < 8; ++j) v[j] = (_Float16)(wcol[kc * 8 + j] * NLOG2E);
            const int u = (ct * 4 + kc) * 16 + c16;
            *reinterpret_cast<half8*>(&sB[u * 8]) = v;
        }
    }
    __syncthreads();

    // ---- phase 1: per-row MLP chain -> d1[32] (relu) -> A fragments ----
    {
        const float* xrow = x + (long)(b0 + tid) * ND;

        float xg[NF];
        #pragma unroll
        for (int f = 0; f < NF; ++f) xg[f] = xrow[s_idx[f]];

        float h0[NH];
        #pragma unroll
        for (int h = 0; h < NH; ++h) h0[h] = s_be0[h];
        #pragma unroll
        for (int f = 0; f < NF; ++f) {
            #pragma unroll
            for (int h = 0; h < NH; ++h)
                h0[h] = fmaf(xg[f], s_We0[f * NH + h], h0[h]);
        }
        // no ReLU on h0

        float h1[NL];
        #pragma unroll
        for (int l = 0; l < NL; ++l) h1[l] = s_be1[l];
        #pragma unroll
        for (int h = 0; h < NH; ++h) {
            #pragma unroll
            for (int l = 0; l < NL; ++l)
                h1[l] = fmaf(h0[h], s_We1[h * NL + l], h1[l]);
        }
        #pragma unroll
        for (int l = 0; l < NL; ++l) h1[l] = fmaxf(h1[l], 0.0f);

        float zz[NL];
        #pragma unroll
        for (int m = 0; m < NL; ++m) zz[m] = s_bl[m];
        #pragma unroll
        for (int l = 0; l < NL; ++l) {
            #pragma unroll
            for (int m = 0; m < NL; ++m)
                zz[m] = fmaf(h1[l], s_Wl[l * NL + m], zz[m]);
        }
        #pragma unroll
        for (int m = 0; m < NL; ++m) zz[m] = fmaxf(zz[m], 0.0f);

        float d0[NH];
        #pragma unroll
        for (int h = 0; h < NH; ++h) d0[h] = s_bd0[h];
        #pragma unroll
        for (int l = 0; l < NL; ++l) {
            #pragma unroll
            for (int h = 0; h < NH; ++h)
                d0[h] = fmaf(zz[l], s_Wd0[l * NH + h], d0[h]);
        }
        // no ReLU on d0

        float d1[NF];
        #pragma unroll
        for (int f = 0; f < NF; ++f) d1[f] = s_bd1[f];
        #pragma unroll
        for (int h = 0; h < NH; ++h) {
            #pragma unroll
            for (int f = 0; f < NF; ++f)
                d1[f] = fmaf(d0[h], s_Wd1[h * NF + f], d1[f]);
        }

        const int t = tid >> 4, r16 = tid & 15;
        #pragma unroll
        for (int kc = 0; kc < 4; ++kc) {
            half8 v;
            #pragma unroll
            for (int j = 0; j < 8; ++j)
                v[j] = (_Float16)fmaxf(d1[kc * 8 + j], 0.0f);   // relu on d1
            const int u = (t * 4 + kc) * 16 + r16;
            *reinterpret_cast<half8*>(&sA[u * 8]) = v;
        }
    }
    __syncthreads();

    // ---- phase 2: frags -> registers, then the pool is repack space ----
    const int w   = tid >> 6;     // wave id: row-tiles [4w, 4w+4)
    const int l   = tid & 63;
    const int r16 = l & 15;       // output row within tile
    const int cq  = (l >> 4) * 4; // output col quad base within col-tile

    half8 bfr[16];
    #pragma unroll
    for (int ct = 0; ct < 16; ++ct)
        bfr[ct] = *reinterpret_cast<const half8*>(&sB[(ct * 64 + l) * 8]);
    half8 afr[4];
    #pragma unroll
    for (int i = 0; i < 4; ++i)
        afr[i] = *reinterpret_cast<const half8*>(&sA[((w * 4 + i) * 64 + l) * 8]);

    __syncthreads();   // frags in registers everywhere; pool free for repack

    // ---- MFMA + sigmoid -> repack -> fill-pattern plain dword stores ----
    {
        float* rep = &sPool[w * 16 * S_REP];   // this wave's 16x256 tile (padded)

        #pragma unroll
        for (int i = 0; i < 4; ++i) {
            const int rt = w * 4 + i;

            // compute & scatter one 16x256 row-tile into LDS
            #pragma unroll
            for (int ct = 0; ct < 16; ++ct) {
                floatx4 acc = *reinterpret_cast<const floatx4*>(&sBias[ct * 16 + cq]);
                acc = __builtin_amdgcn_mfma_f32_16x16x32_f16(bfr[ct], afr[i], acc, 0, 0, 0);
                floatx4 o;
                o.x = sig2(acc[0]);
                o.y = sig2(acc[1]);
                o.z = sig2(acc[2]);
                o.w = sig2(acc[3]);
                *reinterpret_cast<floatx4*>(&rep[r16 * S_REP + ct * 16 + cq]) = o;
            }

            // read back as per-lane dwords (lane l holds cols l,64+l,128+l,192+l)
            float seg[16][4];
            #pragma unroll
            for (int r = 0; r < 16; ++r) {
                #pragma unroll
                for (int s = 0; s < 4; ++s)
                    seg[r][s] = rep[r * S_REP + s * 64 + l];   // ds_read_b32, 2-way alias
            }
            // fill-pattern stores: plain dword, 64 lanes x 4B = 256B segment
            float* obase = out + ((long)e * NB + b0 + rt * 16) * ND + l;
            #pragma unroll
            for (int r = 0; r < 16; ++r) {
                #pragma unroll
                for (int s = 0; s < 4; ++s)
                    obase[(long)r * ND + s * 64] = seg[r][s];   // plain global_store_dword
            }
        }
    }
}

extern "C" void kernel_launch(void* const* d_in, const int* in_sizes, int n_in,
                              void* d_out, int out_size, void* d_ws, size_t ws_size,
                              hipStream_t stream) {
    const float* x   = (const float*)d_in[0];
    const int*   idx = (const int*)  d_in[1];
    const float* We0 = (const float*)d_in[2];
    const float* be0 = (const float*)d_in[3];
    const float* We1 = (const float*)d_in[4];
    const float* be1 = (const float*)d_in[5];
    const float* Wl  = (const float*)d_in[6];
    const float* bl  = (const float*)d_in[7];
    const float* Wd0 = (const float*)d_in[8];
    const float* bd0 = (const float*)d_in[9];
    const float* Wd1 = (const float*)d_in[10];
    const float* bd1 = (const float*)d_in[11];
    const float* Wo  = (const float*)d_in[12];
    const float* bo  = (const float*)d_in[13];
    float* out = (float*)d_out;

    dim3 grid(NB / BT, NE);
    dim3 block(256);
    hipLaunchKernelGGL(bagae_mfma, grid, block, 0, stream,
                       x, idx, We0, be0, We1, be1, Wl, bl,
                       Wd0, bd0, Wd1, bd1, Wo, bo, out);
}

// Round 20
// 107.698 us; speedup vs baseline: 1.2661x; 1.2661x over previous
//
#include <hip/hip_runtime.h>
#include <hip/hip_bf16.h>

#define NE 100
#define NB 4096
#define ND 256
#define NF 32
#define NH 16
#define NL 8
#define BT 128        // batch rows per block (halved: finer grid for tail + phase diversity)
#define NT_ 128       // threads per block (2 waves)
#define S_REP 264     // repack row stride in floats (264 mod 32 = 8 -> bank stagger)

typedef float    floatx4 __attribute__((ext_vector_type(4)));
typedef _Float16 half8   __attribute__((ext_vector_type(8)));

#define NLOG2E -1.44269504088896f

__device__ __forceinline__ float sig2(float a) {   // a = -log2e*x ; sigmoid(x)
    return __builtin_amdgcn_rcpf(1.0f + __builtin_amdgcn_exp2f(a));
}

// R16 structure (row-pipelined MFMA + repack + 1KB-row NT stores, best=115.5us)
// at BT=128 / 128-thread blocks: LDS ~38KB -> 4 blocks/CU (8 waves, same as
// R16) but as 4 INDEPENDENT blocks at staggered phases (store duty cycle up)
// and 3200-block grid (12.5 rounds/CU -> tail quantum halved).
__global__ __launch_bounds__(128, 2)
void bagae_mfma(const float* __restrict__ x,
                const int* __restrict__ idx,
                const float* __restrict__ We0, const float* __restrict__ be0,
                const float* __restrict__ We1, const float* __restrict__ be1,
                const float* __restrict__ Wl,  const float* __restrict__ bl,
                const float* __restrict__ Wd0, const float* __restrict__ bd0,
                const float* __restrict__ Wd1, const float* __restrict__ bd1,
                const float* __restrict__ Wo,  const float* __restrict__ bo,
                float* __restrict__ out)
{
    // pool: 2 waves x 16 x S_REP floats = 33,792B.
    // staging aliases: sA = bytes [0,8K) (128x32 fp16), sB = [8K,24K) (256x32 fp16);
    // both dead after frag->reg load (barrier-separated).
    __shared__ float sPool[2 * 16 * S_REP];
    __shared__ float sBias[ND];          // -log2e * bo_e
    __shared__ float s_We0[NF * NH];
    __shared__ float s_We1[NH * NL];
    __shared__ float s_Wl [NL * NL];
    __shared__ float s_Wd0[NL * NH];
    __shared__ float s_Wd1[NH * NF];
    __shared__ float s_be0[NH], s_be1[NL], s_bl[NL], s_bd0[NH], s_bd1[NF];
    __shared__ int   s_idx[NF];

    _Float16* sA = reinterpret_cast<_Float16*>(sPool);           // 128x32 fp16 = 8KB
    _Float16* sB = reinterpret_cast<_Float16*>(sPool) + BT * NF; // 256x32 fp16 = 16KB

    const int tid = threadIdx.x;
    const int e   = blockIdx.y;
    const int b0  = blockIdx.x * BT;

    // ---- stage small per-estimator weights + scaled output bias ----
    {
        const float* We0e = We0 + e * (NF * NH);
        const float* Wd1e = Wd1 + e * (NH * NF);
        for (int i = tid; i < NF * NH; i += NT_) { s_We0[i] = We0e[i]; s_Wd1[i] = Wd1e[i]; }
        for (int i = tid; i < ND; i += NT_) sBias[i] = bo[e * ND + i] * NLOG2E;
        if (tid < NH * NL) { s_We1[tid] = We1[e * NH * NL + tid];
                             s_Wd0[tid] = Wd0[e * NL * NH + tid]; }
        if (tid < NL * NL) { s_Wl[tid]  = Wl [e * NL * NL + tid]; }
        if (tid < NF)      { s_idx[tid] = idx[e * NF + tid];
                             s_bd1[tid] = bd1[e * NF + tid]; }
        if (tid < NH)      { s_be0[tid] = be0[e * NH + tid];
                             s_bd0[tid] = bd0[e * NH + tid]; }
        if (tid < NL)      { s_be1[tid] = be1[e * NL + tid];
                             s_bl [tid] = bl [e * NL + tid]; }
    }

    // ---- stage B = (-log2e * Wo_e) columns {tid, tid+128} as fp16 frags ----
    // unit u(tile,kc,i16) = tile*64 + kc*16 + i16 (16B units); lane l of
    // tile t reads unit t*64+l -> linear, conflict-free.
    {
        const float* Woe = Wo + (long)e * NF * ND;
        #pragma unroll
        for (int cc = 0; cc < 2; ++cc) {
            const int c = tid + cc * NT_;
            float wcol[NF];
            #pragma unroll
            for (int k = 0; k < NF; ++k) wcol[k] = Woe[k * ND + c];   // coalesced
            const int ct = c >> 4, c16 = c & 15;
            #pragma unroll
            for (int kc = 0; kc < 4; ++kc) {
                half8 v;
                #pragma unroll
                for (int j = 0; j < 8; ++j) v[j] = (_Float16)(wcol[kc * 8 + j] * NLOG2E);
                const int u = (ct * 4 + kc) * 16 + c16;
                *reinterpret_cast<half8*>(&sB[u * 8]) = v;
            }
        }
    }
    __syncthreads();

    // ---- phase 1: per-row MLP chain -> d1[32] (relu) -> A fragments ----
    {
        const float* xrow = x + (long)(b0 + tid) * ND;

        float xg[NF];
        #pragma unroll
        for (int f = 0; f < NF; ++f) xg[f] = xrow[s_idx[f]];

        float h0[NH];
        #pragma unroll
        for (int h = 0; h < NH; ++h) h0[h] = s_be0[h];
        #pragma unroll
        for (int f = 0; f < NF; ++f) {
            #pragma unroll
            for (int h = 0; h < NH; ++h)
                h0[h] = fmaf(xg[f], s_We0[f * NH + h], h0[h]);
        }
        // no ReLU on h0

        float h1[NL];
        #pragma unroll
        for (int l = 0; l < NL; ++l) h1[l] = s_be1[l];
        #pragma unroll
        for (int h = 0; h < NH; ++h) {
            #pragma unroll
            for (int l = 0; l < NL; ++l)
                h1[l] = fmaf(h0[h], s_We1[h * NL + l], h1[l]);
        }
        #pragma unroll
        for (int l = 0; l < NL; ++l) h1[l] = fmaxf(h1[l], 0.0f);

        float zz[NL];
        #pragma unroll
        for (int m = 0; m < NL; ++m) zz[m] = s_bl[m];
        #pragma unroll
        for (int l = 0; l < NL; ++l) {
            #pragma unroll
            for (int m = 0; m < NL; ++m)
                zz[m] = fmaf(h1[l], s_Wl[l * NL + m], zz[m]);
        }
        #pragma unroll
        for (int m = 0; m < NL; ++m) zz[m] = fmaxf(zz[m], 0.0f);

        float d0[NH];
        #pragma unroll
        for (int h = 0; h < NH; ++h) d0[h] = s_bd0[h];
        #pragma unroll
        for (int l = 0; l < NL; ++l) {
            #pragma unroll
            for (int h = 0; h < NH; ++h)
                d0[h] = fmaf(zz[l], s_Wd0[l * NH + h], d0[h]);
        }
        // no ReLU on d0

        float d1[NF];
        #pragma unroll
        for (int f = 0; f < NF; ++f) d1[f] = s_bd1[f];
        #pragma unroll
        for (int h = 0; h < NH; ++h) {
            #pragma unroll
            for (int f = 0; f < NF; ++f)
                d1[f] = fmaf(d0[h], s_Wd1[h * NF + f], d1[f]);
        }

        const int t = tid >> 4, r16 = tid & 15;   // tiles 0..7
        #pragma unroll
        for (int kc = 0; kc < 4; ++kc) {
            half8 v;
            #pragma unroll
            for (int j = 0; j < 8; ++j)
                v[j] = (_Float16)fmaxf(d1[kc * 8 + j], 0.0f);   // relu on d1
            const int u = (t * 4 + kc) * 16 + r16;
            *reinterpret_cast<half8*>(&sA[u * 8]) = v;
        }
    }
    __syncthreads();

    // ---- phase 2: frags -> registers, then the pool is repack space ----
    const int w   = tid >> 6;     // wave id (0,1): row-tiles [4w, 4w+4)
    const int l   = tid & 63;
    const int r16 = l & 15;       // output row within tile
    const int cq  = (l >> 4) * 4; // output col quad base within col-tile

    half8 bfr[16];
    #pragma unroll
    for (int ct = 0; ct < 16; ++ct)
        bfr[ct] = *reinterpret_cast<const half8*>(&sB[(ct * 64 + l) * 8]);
    half8 afr[4];
    #pragma unroll
    for (int i = 0; i < 4; ++i)
        afr[i] = *reinterpret_cast<const half8*>(&sA[((w * 4 + i) * 64 + l) * 8]);

    __syncthreads();   // frags in registers everywhere; pool free for repack

    // ---- row-pipelined: store tile i-1 rows interleaved with tile i compute ----
    {
        float* rep = &sPool[w * 16 * S_REP];   // this wave's 16x256 tile (padded)
        const long orow0 = (long)e * NB + b0 + w * 64;   // first row of this wave

        #define COMPUTE_CT(i_, ct_)                                                     \
        {                                                                               \
            floatx4 acc = *reinterpret_cast<const floatx4*>(&sBias[(ct_) * 16 + cq]);   \
            acc = __builtin_amdgcn_mfma_f32_16x16x32_f16(bfr[(ct_)], afr[(i_)], acc, 0, 0, 0); \
            floatx4 o;                                                                  \
            o.x = sig2(acc[0]);                                                         \
            o.y = sig2(acc[1]);                                                         \
            o.z = sig2(acc[2]);                                                         \
            o.w = sig2(acc[3]);                                                         \
            *reinterpret_cast<floatx4*>(&rep[r16 * S_REP + (ct_) * 16 + cq]) = o;       \
        }

        // prologue: compute tile 0, pull its 16 rows into VGPRs
        #pragma unroll
        for (int ct = 0; ct < 16; ++ct) COMPUTE_CT(0, ct)
        floatx4 rows[16];
        #pragma unroll
        for (int r = 0; r < 16; ++r)
            rows[r] = *reinterpret_cast<const floatx4*>(&rep[r * S_REP + 4 * l]);

        #pragma unroll
        for (int i = 1; i < 4; ++i) {
            float* obase = out + (orow0 + (long)(i - 1) * 16) * ND + 4 * l;
            #pragma unroll
            for (int r = 0; r < 16; ++r) {
                // 1KB full-row NT store of tile i-1 row r ...
                __builtin_nontemporal_store(rows[r],
                    reinterpret_cast<floatx4*>(obase + (long)r * ND));
                // ... followed by ~20 compute instructions of tile i
                COMPUTE_CT(i, r)
            }
            #pragma unroll
            for (int r = 0; r < 16; ++r)
                rows[r] = *reinterpret_cast<const floatx4*>(&rep[r * S_REP + 4 * l]);
        }
        // epilogue: store tile 3
        {
            float* obase = out + (orow0 + 48) * ND + 4 * l;
            #pragma unroll
            for (int r = 0; r < 16; ++r)
                __builtin_nontemporal_store(rows[r],
                    reinterpret_cast<floatx4*>(obase + (long)r * ND));
        }
        #undef COMPUTE_CT
    }
}

extern "C" void kernel_launch(void* const* d_in, const int* in_sizes, int n_in,
                              void* d_out, int out_size, void* d_ws, size_t ws_size,
                              hipStream_t stream) {
    const float* x   = (const float*)d_in[0];
    const int*   idx = (const int*)  d_in[1];
    const float* We0 = (const float*)d_in[2];
    const float* be0 = (const float*)d_in[3];
    const float* We1 = (const float*)d_in[4];
    const float* be1 = (const float*)d_in[5];
    const float* Wl  = (const float*)d_in[6];
    const float* bl  = (const float*)d_in[7];
    const float* Wd0 = (const float*)d_in[8];
    const float* bd0 = (const float*)d_in[9];
    const float* Wd1 = (const float*)d_in[10];
    const float* bd1 = (const float*)d_in[11];
    const float* Wo  = (const float*)d_in[12];
    const float* bo  = (const float*)d_in[13];
    float* out = (float*)d_out;

    dim3 grid(NB / BT, NE);
    dim3 block(NT_);
    hipLaunchKernelGGL(bagae_mfma, grid, block, 0, stream,
                       x, idx, We0, be0, We1, be1, Wl, bl,
                       Wd0, bd0, Wd1, bd1, Wo, bo, out);
}